// Round 5
// baseline (947.636 us; speedup 1.0000x reference)
//
#include <hip/hip_runtime.h>
#include <hip/hip_bf16.h>
#include <cmath>

#define BB 32
#define SS 256
#define DD 1024
#define EE 256
#define FDIM 2048
#define HH 512
#define KOUT (7 * DD)
#define NROW (BB * SS)          // 8192 rows per side
#define NROW2 (2 * NROW)        // 16384 combined

static constexpr float SCALE = 1.0f / 32.0f;   // 1/sqrt(1024)
static constexpr float EPSF  = 1e-13f;

typedef __attribute__((ext_vector_type(8))) short bf16x8;
typedef __attribute__((ext_vector_type(4))) float f32x4;

__device__ inline float4 ld4(const float* p) { return *(const float4*)p; }
__device__ inline ushort f2b(float f) {
    uint x = __float_as_uint(f);
    x += 0x7fffu + ((x >> 16) & 1u);      // round-to-nearest-even
    return (ushort)(x >> 16);
}
__device__ inline float b2f(ushort u) { return __uint_as_float(((uint)u) << 16); }
__device__ inline bf16x8 cvt8(const float* v) {
    bf16x8 r;
#pragma unroll
    for (int j = 0; j < 8; ++j) r[j] = (short)f2b(v[j]);
    return r;
}
__device__ inline void b2f8(bf16x8 v, float* o) {
#pragma unroll
    for (int j = 0; j < 8; ++j) o[j] = b2f((ushort)v[j]);
}
__device__ inline bf16x8 ldf8(const float* p) {
    const float4 u0 = ld4(p), u1 = ld4(p + 4);
    float v[8] = {u0.x, u0.y, u0.z, u0.w, u1.x, u1.y, u1.z, u1.w};
    return cvt8(v);
}

// async global->LDS, 16B per lane; LDS dest = wave-uniform base + lane*16
typedef __attribute__((address_space(1))) const uchar gas_t;
typedef __attribute__((address_space(3))) uchar las_t;
__device__ inline void gll16(const ushort* g, ushort* l) {
    __builtin_amdgcn_global_load_lds((gas_t*)g, (las_t*)l, 16, 0, 0);
}

// XCD-chunked swizzle (grid total must be %8==0)
__device__ inline int swz_orig_2d() {
    const int n   = blockIdx.y * gridDim.x + blockIdx.x;
    const int tot = gridDim.x * gridDim.y;
    return (n & 7) * (tot >> 3) + (n >> 3);
}
__device__ inline int swz_orig_3d() {
    const int n   = (blockIdx.z * gridDim.y + blockIdx.y) * gridDim.x + blockIdx.x;
    const int tot = gridDim.x * gridDim.y * gridDim.z;
    return (n & 7) * (tot >> 3) + (n >> 3);
}

// =========================== prep: transpose + f32->bf16 ===========================
__global__ __launch_bounds__(256)
void tpose_cvt_k(const float* __restrict__ in, ushort* __restrict__ out,
                 int K, int N, size_t inStride, size_t outStride) {
    __shared__ float T[32][33];
    const float* ib = in  + (size_t)blockIdx.z * inStride;
    ushort*      ob = out + (size_t)blockIdx.z * outStride;
    const int k0 = blockIdx.x * 32, n0 = blockIdx.y * 32;
    const int tx = threadIdx.x & 31, ty = threadIdx.x >> 5;
#pragma unroll
    for (int i = 0; i < 4; ++i) T[ty + 8 * i][tx] = ib[(size_t)(k0 + ty + 8 * i) * N + n0 + tx];
    __syncthreads();
#pragma unroll
    for (int i = 0; i < 4; ++i)
        ob[(size_t)(n0 + ty + 8 * i) * K + k0 + tx] = f2b(T[tx][ty + 8 * i]);
}

// post-lin prep: Xb = bf16(x), prodb = bf16(x*att)   (both [16384][1024], alias catb)
__global__ __launch_bounds__(256)
void prep_xprod_k(const float* __restrict__ P, const float* __restrict__ H,
                  const ushort* __restrict__ attAb,
                  ushort* __restrict__ Xb, ushort* __restrict__ prodb) {
    const int idx = blockIdx.x * 256 + threadIdx.x;       // 0 .. NROW2*DD/8-1
    const int row = idx >> 7, chunk = idx & 127;
    const size_t off = (size_t)row * DD + chunk * 8;
    const float* X = (row < NROW) ? (P + off) : (H + off - (size_t)NROW * DD);
    const float4 x0 = ld4(X), x1 = ld4(X + 4);
    float xv[8] = {x0.x, x0.y, x0.z, x0.w, x1.x, x1.y, x1.z, x1.w};
    float av[8];
    b2f8(*(const bf16x8*)&attAb[off], av);
    float pv[8];
#pragma unroll
    for (int j = 0; j < 8; ++j) pv[j] = xv[j] * av[j];
    *(bf16x8*)&Xb[off]    = cvt8(xv);
    *(bf16x8*)&prodb[off] = cvt8(pv);
}

// =========================== softmax (IN-PLACE on sim buffers) ===========================
__global__ __launch_bounds__(256)
void softmax4_k(float* __restrict__ simPH, float* __restrict__ simPHT,
                float* __restrict__ simPP, float* __restrict__ simHH,
                const int* __restrict__ pma, const int* __restrict__ hma) {
    const int job = blockIdx.y;
    float* buf = job == 0 ? simPH : job == 1 ? simPHT : job == 2 ? simPP : simHH;
    const int* mask = job == 0 ? hma : job == 1 ? pma : nullptr;

    __shared__ float  redm[4];
    __shared__ float2 reds[4];
    const int row = blockIdx.x;
    const int b   = row >> 8;
    const int j   = threadIdx.x;
    const float v = buf[(size_t)row * SS + j];
    float mj = 1.0f, z = v;
    if (mask) { mj = (float)mask[b * SS + j]; z = v * mj; }
    float M = z;
#pragma unroll
    for (int off = 1; off < 64; off <<= 1) M = fmaxf(M, __shfl_xor(M, off));
    const int wid = j >> 6;
    if ((j & 63) == 0) redm[wid] = M;
    __syncthreads();
    M = fmaxf(fmaxf(redm[0], redm[1]), fmaxf(redm[2], redm[3]));
    const float e = expf(z - M);
    const float r = e * mj;
    float sz = e, sr = r;
#pragma unroll
    for (int off = 1; off < 64; off <<= 1) {
        sz += __shfl_xor(sz, off);
        sr += __shfl_xor(sr, off);
    }
    if ((j & 63) == 0) reds[wid] = make_float2(sz, sr);
    __syncthreads();
    const float Z  = reds[0].x + reds[1].x + reds[2].x + reds[3].x;
    const float Sm = reds[0].y + reds[1].y + reds[2].y + reds[3].y;
    buf[(size_t)row * SS + j] = mask ? (r / (Sm + EPSF * Z)) : (e / Z);
}

__global__ __launch_bounds__(256)
void colsum4_k(const float* __restrict__ spA, const float* __restrict__ shA,
               const float* __restrict__ hp, const float* __restrict__ ph,
               float* __restrict__ impS, float* __restrict__ impI) {
    const int job = blockIdx.y, b = blockIdx.x, j = threadIdx.x;
    const float* src = job == 0 ? spA : job == 1 ? shA : job == 2 ? hp : ph;
    float* dst = job == 0 ? impS : job == 1 ? impS + NROW : job == 2 ? impI : impI + NROW;
    const float* Mb = src + (size_t)b * SS * SS;
    float s = 0.f;
    for (int i = 0; i < SS; ++i) s += Mb[i * SS + j];
    dst[b * SS + j] = s;
}

// =========================== MFMA common ===========================
// LDS layout [4 kgrp][128 row][8 bf16] — linear in global_load_lds lane order;
// fragment reads hit 16 consecutive 16B chunks (bank-conflict-free).
#define MFMA_CORE()                                                                  \
    {                                                                                \
        bf16x8 afr[4], bfr[4];                                                       \
        _Pragma("unroll") for (int m = 0; m < 4; ++m)                                \
            afr[m] = *(const bf16x8*)As[kq][wr + m * 16 + fr];                       \
        _Pragma("unroll") for (int n = 0; n < 4; ++n)                                \
            bfr[n] = *(const bf16x8*)Bs[kq][wc + n * 16 + fr];                       \
        _Pragma("unroll") for (int m = 0; m < 4; ++m)                                \
            _Pragma("unroll") for (int n = 0; n < 4; ++n)                            \
                acc[m][n] = __builtin_amdgcn_mfma_f32_16x16x32_bf16(                 \
                    afr[m], bfr[n], acc[m][n], 0, 0, 0);                             \
    }

#define MFMA_PREAMBLE()                                                              \
    const int tid = threadIdx.x;                                                     \
    const int lane = tid & 63;                                                       \
    const int w = tid >> 6;                                                          \
    const int wr = (w >> 1) * 64, wc = (w & 1) * 64;                                 \
    const int fr = lane & 15;                                                        \
    const int kq = lane >> 4;                                                        \
    const int rq = kq * 4;                                                           \
    f32x4 acc[4][4] = {};

// wave w stages k-group w for all 128 rows of a tile (2 instrs/wave, 16B/lane)
#define GLL_STAGE(seg, pitch, r0, kloc, LDSARR)                                      \
    {                                                                                \
        const ushort* g0_ = (seg) + (size_t)((r0) + lane) * (pitch) + (kloc) + w * 8;\
        gll16(g0_, &LDSARR[w][0][0]);                                                \
        gll16(g0_ + (size_t)64 * (pitch), &LDSARR[w][64][0]);                        \
    }

// ---- sim GEMMs (NT): g0 P@H^T(+T), g1 P@P^T, g2 H@H^T; f32 in, f32 out ----
__global__ __launch_bounds__(256)
void mfma_nt_k(const float* __restrict__ P, const float* __restrict__ H,
               float* __restrict__ simPH, float* __restrict__ simPHT,
               float* __restrict__ simPP, float* __restrict__ simHH) {
    __shared__ __align__(16) ushort As[4][128][8];
    __shared__ __align__(16) ushort Bs[4][128][8];
    int orig = swz_orig_3d();                 // grid (2,2,96)
    const int cb = orig & 1; orig >>= 1;
    const int rb = orig & 1; orig >>= 1;
    const int g = orig >> 5, b = orig & 31;
    const float* Au = ((g == 2) ? H : P) + (size_t)b * SS * DD;
    const float* Bu = ((g == 1) ? P : H) + (size_t)b * SS * DD;
    const int col0 = cb * 128, row0 = rb * 128;
    MFMA_PREAMBLE();
    for (int k0 = 0; k0 < DD; k0 += 32) {
        bf16x8 ar[2], br[2];
#pragma unroll
        for (int i = 0; i < 2; ++i) {
            const int cid = tid + i * 256, srow = cid >> 2, skc = (cid & 3) * 8;
            ar[i] = ldf8(&Au[(size_t)(row0 + srow) * DD + k0 + skc]);
            br[i] = ldf8(&Bu[(size_t)(col0 + srow) * DD + k0 + skc]);
        }
        __syncthreads();
#pragma unroll
        for (int i = 0; i < 2; ++i) {
            const int cid = tid + i * 256;
            *(bf16x8*)As[cid & 3][cid >> 2] = ar[i];
            *(bf16x8*)Bs[cid & 3][cid >> 2] = br[i];
        }
        __syncthreads();
        MFMA_CORE();
    }
    float* Cb = (g == 0 ? simPH : g == 1 ? simPP : simHH) + (size_t)b * SS * SS;
#pragma unroll
    for (int m = 0; m < 4; ++m)
#pragma unroll
        for (int n = 0; n < 4; ++n) {
            const int c = col0 + wc + n * 16 + fr;
            const int r0 = row0 + wr + m * 16 + rq;
#pragma unroll
            for (int r = 0; r < 4; ++r) Cb[(size_t)(r0 + r) * SS + c] = acc[m][n][r] * SCALE;
            if (g == 0) {
                float* Tb = simPHT + (size_t)b * SS * SS;
                *(float4*)&Tb[(size_t)c * SS + r0] =
                    make_float4(acc[m][n][0] * SCALE, acc[m][n][1] * SCALE,
                                acc[m][n][2] * SCALE, acc[m][n][3] * SCALE);
            }
        }
}

// ---- att GEMMs: g0 att_p=ph@Hb (mask pm), g1 att_h=hp@P (mask hm), g2 self_p, g3 self_h
__global__ __launch_bounds__(256)
void mfma_att_k(const float* __restrict__ ph, const float* __restrict__ hp,
                const float* __restrict__ spA, const float* __restrict__ shA,
                const ushort* __restrict__ PbT, const ushort* __restrict__ HbT,
                const int* __restrict__ pma, const int* __restrict__ hma,
                ushort* __restrict__ attAb, ushort* __restrict__ selfAb) {
    __shared__ __align__(16) ushort As[4][128][8];
    __shared__ __align__(16) ushort Bs[4][128][8];
    int orig = swz_orig_3d();                 // grid (8,2,128)
    const int x = orig & 7; orig >>= 3;
    const int y = orig & 1; orig >>= 1;
    const int g = orig >> 5, b = orig & 31;
    const float*  W  = (g == 0 ? ph : g == 1 ? hp : g == 2 ? spA : shA) + (size_t)b * SS * SS;
    const ushort* BT = ((g == 0 || g == 3) ? HbT : PbT) + (size_t)b * DD * SS;
    const int* rmask = g == 0 ? pma + b * SS : g == 1 ? hma + b * SS : nullptr;
    const int side = (g == 1 || g == 3);
    ushort* Ob = (g < 2 ? attAb : selfAb) + ((size_t)side * NROW + (size_t)b * SS) * DD;
    const int col0 = x * 128, row0 = y * 128;
    MFMA_PREAMBLE();
    for (int k0 = 0; k0 < SS; k0 += 32) {
        bf16x8 ar[2];
#pragma unroll
        for (int i = 0; i < 2; ++i) {
            const int cid = tid + i * 256, srow = cid >> 2, skc = (cid & 3) * 8;
            ar[i] = ldf8(&W[(size_t)(row0 + srow) * SS + k0 + skc]);
        }
        __syncthreads();
        GLL_STAGE(BT, SS, col0, k0, Bs);
#pragma unroll
        for (int i = 0; i < 2; ++i) {
            const int cid = tid + i * 256;
            *(bf16x8*)As[cid & 3][cid >> 2] = ar[i];
        }
        __syncthreads();
        MFMA_CORE();
    }
#pragma unroll
    for (int m = 0; m < 4; ++m)
#pragma unroll
        for (int n = 0; n < 4; ++n) {
            const int c = col0 + wc + n * 16 + fr;
#pragma unroll
            for (int r = 0; r < 4; ++r) {
                const int rr = row0 + wr + m * 16 + rq + r;
                const float mm = rmask ? (float)rmask[rr] : 1.0f;
                Ob[(size_t)rr * DD + c] = f2b(acc[m][n][r] * mm);
            }
        }
}

// ---- fuse: catb[row, kf*256+e]; rows 0..16383; X read from f32 P/H ----
__global__ __launch_bounds__(256)
void mfma_fuse_k(const float* __restrict__ P, const float* __restrict__ H,
                 const float* __restrict__ impS, const float* __restrict__ impI,
                 const ushort* __restrict__ W8T, const float* __restrict__ B8v,
                 ushort* __restrict__ catb) {
    __shared__ __align__(16) ushort As[4][128][8];
    __shared__ __align__(16) ushort Bs[4][128][8];
    const int orig = swz_orig_2d();           // grid (16,128)
    const int cb = orig & 15, rb = orig >> 4;
    const int kf = cb >> 1, e0 = (cb & 1) * 128, row0 = rb * 128;
    const float* X = (row0 < NROW) ? P : H;
    const int rbase = (row0 < NROW) ? row0 : row0 - NROW;
    MFMA_PREAMBLE();
    const ushort* Wk = W8T + (size_t)kf * EE * DD;

    int srow_[2]; float sA[2], iA[2], cf[2];
#pragma unroll
    for (int i = 0; i < 2; ++i) {
        const int cid = tid + i * 256;
        srow_[i] = cid >> 2;
        const int row = row0 + srow_[i];
        const float s_ = impS[row], i_ = impI[row];
        sA[i] = s_; iA[i] = i_;
        float c = 0.f;
        switch (kf) {
            case 0: c = s_ * i_;             break;
            case 1: c = s_ + i_;             break;
            case 2: c = fmaxf(s_, i_);       break;
            case 4: c = s_ * i_ + 1.f;       break;
            case 5: c = s_ + i_ + 1.f;       break;
            case 6: c = fmaxf(s_, i_) + 1.f; break;
            default: break;
        }
        cf[i] = c;
    }
    for (int k0 = 0; k0 < DD; k0 += 32) {
        bf16x8 ar[2];
#pragma unroll
        for (int i = 0; i < 2; ++i) {
            const int cid = tid + i * 256, skc = (cid & 3) * 8;
            const float* src = &X[(size_t)(rbase + srow_[i]) * DD + k0 + skc];
            const float4 u0 = ld4(src), u1 = ld4(src + 4);
            float v[8] = {u0.x, u0.y, u0.z, u0.w, u1.x, u1.y, u1.z, u1.w};
            if (kf == 3) {
#pragma unroll
                for (int j = 0; j < 8; ++j) v[j] = fmaxf(v[j] * sA[i], v[j] * iA[i]);
            } else if (kf == 7) {
#pragma unroll
                for (int j = 0; j < 8; ++j) v[j] = fmaxf(v[j] * sA[i], v[j] * iA[i]) + v[j];
            } else {
#pragma unroll
                for (int j = 0; j < 8; ++j) v[j] *= cf[i];
            }
            ar[i] = cvt8(v);
        }
        __syncthreads();
        GLL_STAGE(Wk, DD, e0, k0, Bs);
#pragma unroll
        for (int i = 0; i < 2; ++i) {
            const int cid = tid + i * 256;
            *(bf16x8*)As[cid & 3][cid >> 2] = ar[i];
        }
        __syncthreads();
        MFMA_CORE();
    }
#pragma unroll
    for (int m = 0; m < 4; ++m)
#pragma unroll
        for (int n = 0; n < 4; ++n) {
            const int el = e0 + wc + n * 16 + fr;
            const float bv = B8v[kf * EE + el];
#pragma unroll
            for (int r = 0; r < 4; ++r) {
                const int rr = row0 + wr + m * 16 + rq + r;
                catb[(size_t)rr * FDIM + kf * EE + el] = f2b(acc[m][n][r] + bv);
            }
        }
}

// ---- lin: pall = relu(cat @ Wl + bl); rows 16384; both operands direct-staged ----
__global__ __launch_bounds__(256)
void mfma_lin_k(const ushort* __restrict__ A, const ushort* __restrict__ BT,
                const float* __restrict__ bias, ushort* __restrict__ C) {
    __shared__ __align__(16) ushort As[4][128][8];
    __shared__ __align__(16) ushort Bs[4][128][8];
    const int orig = swz_orig_2d();           // grid (16,128)
    const int col0 = (orig & 15) * 128, row0 = (orig >> 4) * 128;
    MFMA_PREAMBLE();
    for (int k0 = 0; k0 < FDIM; k0 += 32) {
        __syncthreads();
        GLL_STAGE(A,  FDIM, row0, k0, As);
        GLL_STAGE(BT, FDIM, col0, k0, Bs);
        __syncthreads();
        MFMA_CORE();
    }
#pragma unroll
    for (int m = 0; m < 4; ++m)
#pragma unroll
        for (int n = 0; n < 4; ++n) {
            const int c = col0 + wc + n * 16 + fr;
            const float bv = bias[c];
#pragma unroll
            for (int r = 0; r < 4; ++r) {
                const int rr = row0 + wr + m * 16 + rq + r;
                C[(size_t)rr * FDIM + c] = f2b(fmaxf(acc[m][n][r] + bv, 0.f));
            }
        }
}

// ---- out: relu(enh @ Wp + bp); A segments all bf16 (Xb/att/self/pall/prod direct,
//      diff = Xb-att reg-staged); B = WpT direct ----
__global__ __launch_bounds__(256)
void mfma_out_k(const ushort* __restrict__ Xb, const ushort* __restrict__ attAb,
                const ushort* __restrict__ selfAb, const ushort* __restrict__ pallb,
                const ushort* __restrict__ prodb, const ushort* __restrict__ WpT,
                const float* __restrict__ bp, float* __restrict__ out) {
    __shared__ __align__(16) ushort As[4][128][8];
    __shared__ __align__(16) ushort Bs[4][128][8];
    const int orig = swz_orig_2d();           // grid (4,128)
    const int col0 = (orig & 3) * 128, row0 = (orig >> 2) * 128;
    MFMA_PREAMBLE();
    for (int k0 = 0; k0 < KOUT; k0 += 32) {
        const int sidx = k0 >> 10;
        if (sidx == 6) {                       // diff = x - att (reg-staged)
            bf16x8 ar[2];
#pragma unroll
            for (int i = 0; i < 2; ++i) {
                const int cid = tid + i * 256, srow = cid >> 2, skc = (cid & 3) * 8;
                const size_t off = (size_t)(row0 + srow) * DD + (k0 - 6 * DD) + skc;
                float xv[8], av[8], v[8];
                b2f8(*(const bf16x8*)&Xb[off], xv);
                b2f8(*(const bf16x8*)&attAb[off], av);
#pragma unroll
                for (int j = 0; j < 8; ++j) v[j] = xv[j] - av[j];
                ar[i] = cvt8(v);
            }
            __syncthreads();
            GLL_STAGE(WpT, KOUT, col0, k0, Bs);
#pragma unroll
            for (int i = 0; i < 2; ++i) {
                const int cid = tid + i * 256;
                *(bf16x8*)As[cid & 3][cid >> 2] = ar[i];
            }
            __syncthreads();
        } else {
            const ushort* seg; int pitch, kloc;
            switch (sidx) {
                case 0:  seg = Xb;     pitch = DD;   kloc = k0;          break;
                case 1:  seg = attAb;  pitch = DD;   kloc = k0 - DD;     break;
                case 2:  seg = selfAb; pitch = DD;   kloc = k0 - 2 * DD; break;
                case 3:
                case 4:  seg = pallb;  pitch = FDIM; kloc = k0 - 3 * DD; break;
                default: seg = prodb;  pitch = DD;   kloc = k0 - 5 * DD; break;
            }
            __syncthreads();
            GLL_STAGE(seg, pitch, row0, kloc, As);
            GLL_STAGE(WpT, KOUT, col0, k0, Bs);
            __syncthreads();
        }
        MFMA_CORE();
    }
#pragma unroll
    for (int m = 0; m < 4; ++m)
#pragma unroll
        for (int n = 0; n < 4; ++n) {
            const int c = col0 + wc + n * 16 + fr;
            const float bv = bp[c];
#pragma unroll
            for (int r = 0; r < 4; ++r) {
                const int rr = row0 + wr + m * 16 + rq + r;
                out[(size_t)rr * HH + c] = fmaxf(acc[m][n][r] + bv, 0.f);
            }
        }
}

// =========================== launcher ===========================
// Workspace (221.4 MB, proven-safe):
//   region0 (67.1 MB): [4 sims (33.5) | PbT,HbT (33.5)]
//     -> after mfma_att_k reused as catb (67.1)
//     -> after mfma_lin_k reused as Xb (33.5) + prodb (33.5)
//   impS/impI | attAb/selfAb (67.1) | pallb (67.1) | WlT/WpT/W8T (19.4)
extern "C" void kernel_launch(void* const* d_in, const int* in_sizes, int n_in,
                              void* d_out, int out_size, void* d_ws, size_t ws_size,
                              hipStream_t stream) {
    const float* P   = (const float*)d_in[0];
    const float* Hb  = (const float*)d_in[1];
    const int*   pma = (const int*)d_in[2];
    const int*   hma = (const int*)d_in[3];
    const float* W8  = (const float*)d_in[4];
    const float* B8v = (const float*)d_in[5];
    const float* Wl  = (const float*)d_in[6];
    const float* bl  = (const float*)d_in[7];
    const float* Wp  = (const float*)d_in[8];
    const float* bp  = (const float*)d_in[9];

    char* base = (char*)d_ws;
    float* simPH  = (float*)base;
    float* simPHT = simPH  + (size_t)BB * SS * SS;
    float* simPP  = simPHT + (size_t)BB * SS * SS;
    float* simHH  = simPP  + (size_t)BB * SS * SS;
    ushort* PbT   = (ushort*)(simHH + (size_t)BB * SS * SS);
    ushort* HbT   = PbT + (size_t)NROW * DD;
    ushort* catb  = (ushort*)base;                     // alias of region0
    ushort* Xb    = (ushort*)base;                     // alias (post-lin)
    ushort* prodb = Xb + (size_t)NROW2 * DD;           // alias (post-lin)
    char* cur = (char*)(HbT + (size_t)NROW * DD);
    auto alloc_f = [&](size_t n) { float*  p = (float*)cur;  cur += n * 4; return p; };
    auto alloc_u = [&](size_t n) { ushort* p = (ushort*)cur; cur += n * 2; return p; };
    float*  impS   = alloc_f(NROW2);
    float*  impI   = alloc_f(NROW2);
    ushort* attAb  = alloc_u((size_t)NROW2 * DD);
    ushort* selfAb = alloc_u((size_t)NROW2 * DD);
    ushort* pallb  = alloc_u((size_t)NROW2 * FDIM);
    ushort* WlT    = alloc_u((size_t)FDIM * FDIM);
    ushort* WpT    = alloc_u((size_t)HH * KOUT);
    ushort* W8T    = alloc_u((size_t)8 * EE * DD);

    float* outp = (float*)d_out;
    const dim3 blk(256);

    // ---- preps
    tpose_cvt_k<<<dim3(8, 32, BB), blk, 0, stream>>>(P,  PbT, SS, DD, (size_t)SS * DD, (size_t)DD * SS);
    tpose_cvt_k<<<dim3(8, 32, BB), blk, 0, stream>>>(Hb, HbT, SS, DD, (size_t)SS * DD, (size_t)DD * SS);
    tpose_cvt_k<<<dim3(FDIM / 32, FDIM / 32, 1), blk, 0, stream>>>(Wl, WlT, FDIM, FDIM, 0, 0);
    tpose_cvt_k<<<dim3(KOUT / 32, HH / 32, 1), blk, 0, stream>>>(Wp, WpT, KOUT, HH, 0, 0);
    tpose_cvt_k<<<dim3(DD / 32, EE / 32, 8), blk, 0, stream>>>(W8, W8T, DD, EE,
                                                               (size_t)DD * EE, (size_t)EE * DD);

    // ---- attention pipeline
    mfma_nt_k<<<dim3(2, 2, 96), blk, 0, stream>>>(P, Hb, simPH, simPHT, simPP, simHH);
    softmax4_k<<<dim3(NROW, 4), blk, 0, stream>>>(simPH, simPHT, simPP, simHH, pma, hma);
    colsum4_k<<<dim3(BB, 4), blk, 0, stream>>>(simPP, simHH, simPHT, simPH, impS, impI);
    mfma_att_k<<<dim3(8, 2, 128), blk, 0, stream>>>(simPH, simPHT, simPP, simHH, PbT, HbT,
                                                    pma, hma, attAb, selfAb);

    // ---- fused projection pipeline (both sides combined)
    mfma_fuse_k<<<dim3(16, 128), blk, 0, stream>>>(P, Hb, impS, impI, W8T, B8v, catb);
    mfma_lin_k<<<dim3(16, 128), blk, 0, stream>>>(catb, WlT, bl, pallb);
    prep_xprod_k<<<dim3(NROW2 * DD / 8 / 256), blk, 0, stream>>>(P, Hb, attAb, Xb, prodb);
    mfma_out_k<<<dim3(4, 128), blk, 0, stream>>>(Xb, attAb, selfAb, pallb, prodb, WpT, bp, outp);

    (void)in_sizes; (void)n_in; (void)out_size; (void)ws_size;
}